// Round 10
// baseline (91.868 us; speedup 1.0000x reference)
//
#include <hip/hip_runtime.h>
#include <hip/hip_bf16.h>

typedef __attribute__((ext_vector_type(8))) short bf16x8;
typedef __attribute__((ext_vector_type(4))) float f32x4;
typedef __attribute__((ext_vector_type(8))) unsigned short u16x8;

#define KD 2304
#define PL 4232                      // padded plane stride (elems), multiple of 8
#define OUT_PER_B (256 * 1024)

static __device__ __forceinline__ ushort f2bf(float f) {
  union { float f; unsigned int i; } v; v.f = f;
  unsigned int x = v.i;
  x += 0x7fffu + ((x >> 16) & 1u);   // round-to-nearest-even
  return (ushort)(x >> 16);
}

#define GLDS16(gp, lp)                                                         \
  __builtin_amdgcn_global_load_lds(                                            \
      (const __attribute__((address_space(1))) void*)(gp),                     \
      (__attribute__((address_space(3))) void*)(lp), 16, 0, 0)

#define LDSOFF(p) ((unsigned)(size_t)(__attribute__((address_space(3))) const void*)(p))

// naked ds_read: NO memory clobber -> compiler inserts no vmcnt before it
#define DSREAD(dst, addr) \
  asm volatile("ds_read_b128 %0, %1" : "=v"(dst) : "v"(addr))

// ---------------- Kernel 1: separable 4x4 FIR + weight cast ---------------------
__global__ __launch_bounds__(256) void k_fir(const float* __restrict__ x,
                                             ushort* __restrict__ xfn,
                                             const float* __restrict__ w,
                                             ushort* __restrict__ wb) {
  __shared__ float sxp[64 * 76];   // row r at cols 4..67; cols 2,3,68,69 zero halo
  __shared__ float stp[68 * 68];   // h-row i' at row i'+2; rows 0,1,66,67 zero
  const int plane = blockIdx.x;               // 0..4095
  const float* xp = x + (size_t)plane * 4096;
  ushort* op = xfn + (size_t)plane * PL;
  const int t = threadIdx.x;

  if (plane < 2304) {              // fused weight cast
    int iw = plane * 256 + t;
    float v = w[iw];
    int j = iw % 9;
    int t2 = iw / 9;
    int ic = t2 & 255;
    int oc = t2 >> 8;
    wb[oc * KD + j * 256 + ic] = f2bf(v);
  }

  {
    int r = t & 63, cs = t >> 6;
    int col = (cs < 2) ? (2 + cs) : (66 + cs);   // 2,3,68,69
    sxp[r * 76 + col] = 0.f;
  }
  for (int i = t; i < 272; i += 256) {           // 4 rows x 68
    int rr = i / 68, cc = i - rr * 68;
    int row = (rr < 2) ? rr : (64 + rr);         // 0,1,66,67
    stp[row * 68 + cc] = 0.f;
  }

  const float4* x4 = (const float4*)xp;
#pragma unroll
  for (int i = 0; i < 4; ++i) {
    int f4 = t + 256 * i;
    int r = f4 >> 4, w4 = f4 & 15;
    *(float4*)&sxp[r * 76 + 4 + w4 * 4] = x4[f4];
  }
  __syncthreads();

  for (int g = t; g < 1088; g += 256) {
    int i = g / 17, jg = g - i * 17;
    int j0 = jg << 2;
    const float* s = &sxp[i * 76 + j0];
    float4 a0 = *(const float4*)(s);
    float4 a1 = *(const float4*)(s + 4);
    float4 a2 = *(const float4*)(s + 8);
    float4 o;
    o.x = (a0.z + a1.y) + 3.f * (a0.w + a1.x);
    o.y = (a0.w + a1.z) + 3.f * (a1.x + a1.y);
    o.z = (a1.x + a1.w) + 3.f * (a1.y + a1.z);
    o.w = (a1.y + a2.x) + 3.f * (a1.z + a1.w);
    *(float4*)&stp[(i + 2) * 68 + j0] = o;
  }
  __syncthreads();

  for (int g = t; g < 1105; g += 256) {
    int i = g / 17, jg = g - i * 17;
    int j0 = jg << 2;
    const float* s = &stp[i * 68 + j0];
    float4 r0 = *(const float4*)(s);
    float4 r1 = *(const float4*)(s + 68);
    float4 r2 = *(const float4*)(s + 136);
    float4 r3 = *(const float4*)(s + 204);
    float4 o;
    o.x = (r0.x + r3.x) + 3.f * (r1.x + r2.x);
    o.y = (r0.y + r3.y) + 3.f * (r1.y + r2.y);
    o.z = (r0.z + r3.z) + 3.f * (r1.z + r2.z);
    o.w = (r0.w + r3.w) + 3.f * (r1.w + r2.w);
    ushort* q = op + i * 65 + j0;
    q[0] = f2bf(o.x * 0.015625f);
    if (j0 + 1 < 65) q[1] = f2bf(o.y * 0.015625f);
    if (j0 + 2 < 65) q[2] = f2bf(o.z * 0.015625f);
    if (j0 + 3 < 65) q[3] = f2bf(o.w * 0.015625f);
  }
}

// ---------------- Kernel 2: transpose NCHW -> NHWC (bf16), 16B both sides -------
__global__ __launch_bounds__(256) void k_tr(const ushort* __restrict__ xfn,
                                            ushort* __restrict__ xft) {
  __shared__ ushort ld[128 * 66];
  const int hw0 = blockIdx.x * 128;
  const int c0 = blockIdx.y * 64;
  const int b = blockIdx.z;
  const int t = threadIdx.x;

#pragma unroll
  for (int it = 0; it < 4; ++it) {
    int idx = it * 256 + t;                 // 0..1023
    int c = idx >> 4, q = idx & 15;
    u16x8 v = {};
    if (hw0 + q * 8 < 4225)
      v = *(const u16x8*)(xfn + (size_t)(b * 256 + c0 + c) * PL + hw0 + q * 8);
#pragma unroll
    for (int k = 0; k < 8; ++k)
      ld[(q * 8 + k) * 66 + (c ^ (k << 3))] = v[k];
  }
  __syncthreads();
#pragma unroll
  for (int it = 0; it < 4; ++it) {
    int idx = it * 256 + t;
    int hwl = idx >> 3, a = idx & 7;
    int k7 = hwl & 7;
    int hw = hw0 + hwl;
    if (hw < 4225) {
      u16x8 v = *(const u16x8*)&ld[hwl * 66 + ((a ^ k7) << 3)];
      *(u16x8*)&xft[((size_t)(b * 4225 + hw) << 8) + c0 + (a << 3)] = v;
    }
  }
}

// ---------------- Kernel 3: implicit-conv GEMM, A direct-from-L2 ---------------
// C[oc=256][n=16384]; BM=128, BN=128, BK=64; 256 thr, 4 waves (2m x 2n) of 64x64.
// A (1.18 MB, L2-resident) read straight to registers with distance-1 prefetch;
// only B goes through LDS (dbuf 32 KB, counted vmcnt(12): 4 B-glds + 8 A-loads
// per iter stay in flight). LDS/CU-iter: 48 KB (was 96 KB).
__global__ __launch_bounds__(256) void k_gemm3(const ushort* __restrict__ Wb,
                                               const ushort* __restrict__ Xt,
                                               const float* __restrict__ bias,
                                               float* __restrict__ out) {
  __shared__ ushort lB[2][128 * 64];               // 16 KB each
  const int bid = blockIdx.x;                      // 0..255
  const int work = (bid & 7) * 32 + (bid >> 3);    // XCD-chunked bijective
  const int ntile = work >> 1;
  const int mtile = work & 1;
  const int m0 = mtile * 128;
  const int n0 = ntile * 128;
  const int t = threadIdx.x;
  const int wid = t >> 6, lane = t & 63;
  const int wm = wid >> 1, wn = wid & 1;
  const int lrow = lane & 15, kgrp = lane >> 4;

  // B staging sources (pre-swizzled chunk XOR, linear LDS dest)
  const ushort* bB[4];
#pragma unroll
  for (int i = 0; i < 4; ++i) {
    int idx = i * 256 + t;
    int row = idx >> 3;
    int n = n0 + row;
    int b = n >> 10, oh = (n >> 5) & 31, ow = n & 31;
    bB[i] = Xt + ((size_t)((b * 65 + 2 * oh) * 65 + 2 * ow) << 8) +
            (((idx & 7) ^ (row & 7)) << 3);
  }

  // A global fragment pointers: row = m0 + wm*64 + f*16 + lrow, lane k-sub kgrp*8
  const ushort* aP[4];
#pragma unroll
  for (int f = 0; f < 4; ++f)
    aP[f] = Wb + (size_t)(m0 + wm * 64 + f * 16 + lrow) * KD + kgrp * 8;

#define STAGE(buf, kt)                                                         \
  {                                                                            \
    const int j_ = (kt) >> 2;                                                  \
    const int dh_ = j_ / 3, dw_ = j_ - 3 * dh_;                                \
    const int boff_ = (dh_ * 65 + dw_) * 256 + (((kt) & 3) << 6);              \
    _Pragma("unroll") for (int i_ = 0; i_ < 4; ++i_)                           \
        GLDS16(bB[i_] + boff_, &lB[buf][(i_ * 256 + t) * 8]);                  \
  }

#define ALOAD(dst, kt)                                                         \
  _Pragma("unroll") for (int s_ = 0; s_ < 2; ++s_)                             \
  _Pragma("unroll") for (int f_ = 0; f_ < 4; ++f_)                             \
      dst[s_][f_] = *(const bf16x8*)(aP[f_] + (kt) * 64 + s_ * 32);

  // B read addresses (swizzled), buf0
  unsigned bAddr[2][4];
#pragma unroll
  for (int f = 0; f < 4; ++f) {
    int brow = wn * 64 + f * 16 + lrow;
#pragma unroll
    for (int s = 0; s < 2; ++s)
      bAddr[s][f] = LDSOFF(&lB[0][brow * 64 + (((s * 4 + kgrp) ^ brow) & 7) * 8]);
  }

  f32x4 acc[4][4];
#pragma unroll
  for (int i = 0; i < 4; ++i)
#pragma unroll
    for (int j = 0; j < 4; ++j) acc[i][j] = (f32x4){0.f, 0.f, 0.f, 0.f};

  bf16x8 Aa[2][4], Ab[2][4];

#define KSTEP(kt, CUR, NXT)                                                    \
  {                                                                            \
    const int cur_ = (kt) & 1;                                                 \
    if ((kt) < 35) {                                                           \
      STAGE(cur_ ^ 1, (kt) + 1);                                               \
      ALOAD(NXT, (kt) + 1);                                                    \
    }                                                                          \
    __builtin_amdgcn_sched_barrier(0);                                         \
    if ((kt) < 35)                                                             \
      asm volatile("s_waitcnt vmcnt(12)" ::: "memory");                        \
    else                                                                       \
      asm volatile("s_waitcnt vmcnt(0)" ::: "memory");                         \
    __builtin_amdgcn_s_barrier();                                              \
    __builtin_amdgcn_sched_barrier(0);                                         \
    const unsigned off_ = cur_ ? (unsigned)(128 * 64 * 2) : 0u;                \
    _Pragma("unroll") for (int s = 0; s < 2; ++s) {                            \
      bf16x8 Bf0, Bf1, Bf2, Bf3;                                               \
      DSREAD(Bf0, bAddr[s][0] + off_);                                         \
      DSREAD(Bf1, bAddr[s][1] + off_);                                         \
      DSREAD(Bf2, bAddr[s][2] + off_);                                         \
      DSREAD(Bf3, bAddr[s][3] + off_);                                         \
      asm volatile("s_waitcnt lgkmcnt(0)" ::: "memory");                       \
      __builtin_amdgcn_sched_barrier(0);                                       \
      acc[0][0] = __builtin_amdgcn_mfma_f32_16x16x32_bf16(CUR[s][0], Bf0, acc[0][0], 0, 0, 0); \
      acc[0][1] = __builtin_amdgcn_mfma_f32_16x16x32_bf16(CUR[s][0], Bf1, acc[0][1], 0, 0, 0); \
      acc[0][2] = __builtin_amdgcn_mfma_f32_16x16x32_bf16(CUR[s][0], Bf2, acc[0][2], 0, 0, 0); \
      acc[0][3] = __builtin_amdgcn_mfma_f32_16x16x32_bf16(CUR[s][0], Bf3, acc[0][3], 0, 0, 0); \
      acc[1][0] = __builtin_amdgcn_mfma_f32_16x16x32_bf16(CUR[s][1], Bf0, acc[1][0], 0, 0, 0); \
      acc[1][1] = __builtin_amdgcn_mfma_f32_16x16x32_bf16(CUR[s][1], Bf1, acc[1][1], 0, 0, 0); \
      acc[1][2] = __builtin_amdgcn_mfma_f32_16x16x32_bf16(CUR[s][1], Bf2, acc[1][2], 0, 0, 0); \
      acc[1][3] = __builtin_amdgcn_mfma_f32_16x16x32_bf16(CUR[s][1], Bf3, acc[1][3], 0, 0, 0); \
      acc[2][0] = __builtin_amdgcn_mfma_f32_16x16x32_bf16(CUR[s][2], Bf0, acc[2][0], 0, 0, 0); \
      acc[2][1] = __builtin_amdgcn_mfma_f32_16x16x32_bf16(CUR[s][2], Bf1, acc[2][1], 0, 0, 0); \
      acc[2][2] = __builtin_amdgcn_mfma_f32_16x16x32_bf16(CUR[s][2], Bf2, acc[2][2], 0, 0, 0); \
      acc[2][3] = __builtin_amdgcn_mfma_f32_16x16x32_bf16(CUR[s][2], Bf3, acc[2][3], 0, 0, 0); \
      acc[3][0] = __builtin_amdgcn_mfma_f32_16x16x32_bf16(CUR[s][3], Bf0, acc[3][0], 0, 0, 0); \
      acc[3][1] = __builtin_amdgcn_mfma_f32_16x16x32_bf16(CUR[s][3], Bf1, acc[3][1], 0, 0, 0); \
      acc[3][2] = __builtin_amdgcn_mfma_f32_16x16x32_bf16(CUR[s][3], Bf2, acc[3][2], 0, 0, 0); \
      acc[3][3] = __builtin_amdgcn_mfma_f32_16x16x32_bf16(CUR[s][3], Bf3, acc[3][3], 0, 0, 0); \
    }                                                                          \
    __builtin_amdgcn_sched_barrier(0);                                         \
    __builtin_amdgcn_s_barrier();                                              \
  }

  STAGE(0, 0);
  ALOAD(Aa, 0);

  for (int i = 0; i < 18; ++i) {
    KSTEP(2 * i, Aa, Ab);
    KSTEP(2 * i + 1, Ab, Aa);
  }

  f32x4 bv[4];
#pragma unroll
  for (int fm = 0; fm < 4; ++fm)
    bv[fm] = *(const f32x4*)(bias + m0 + wm * 64 + fm * 16 + kgrp * 4);

#pragma unroll
  for (int fm = 0; fm < 4; ++fm) {
#pragma unroll
    for (int fn = 0; fn < 4; ++fn) {
      int nn = n0 + wn * 64 + fn * 16 + lrow;
      int oc = m0 + wm * 64 + fm * 16 + kgrp * 4;
      float* op = out + (size_t)(nn >> 10) * OUT_PER_B + (nn & 1023) +
                  (size_t)oc * 1024;
      op[0]    = acc[fm][fn][0] + bv[fm][0];
      op[1024] = acc[fm][fn][1] + bv[fm][1];
      op[2048] = acc[fm][fn][2] + bv[fm][2];
      op[3072] = acc[fm][fn][3] + bv[fm][3];
    }
  }
}

extern "C" void kernel_launch(void* const* d_in, const int* in_sizes, int n_in,
                              void* d_out, int out_size, void* d_ws, size_t ws_size,
                              hipStream_t stream) {
  const float* x    = (const float*)d_in[0];  // [16,256,64,64]
  const float* w    = (const float*)d_in[1];  // [256,256,3,3]
  const float* bias = (const float*)d_in[2];  // [256]
  float* out = (float*)d_out;                 // [16,256,32,32]

  char* ws = (char*)d_ws;
  ushort* xfn = (ushort*)ws;                        // 4096*4232*2 = 34,668,544 B
  ushort* xft = (ushort*)(ws + 34668544);           // 16*4225*256*2 = 34,611,200 B
  ushort* wb  = (ushort*)(ws + 34668544 + 34611200);// 1,179,648 B

  k_fir<<<4096, 256, 0, stream>>>(x, xfn, w, wb);
  k_tr<<<dim3(34, 4, 16), 256, 0, stream>>>(xfn, xft);
  k_gemm3<<<256, 256, 0, stream>>>(wb, xft, bias, out);
}

// Round 11
// 75.414 us; speedup vs baseline: 1.2182x; 1.2182x over previous
//
#include <hip/hip_runtime.h>
#include <hip/hip_bf16.h>

typedef __attribute__((ext_vector_type(8))) short bf16x8;
typedef __attribute__((ext_vector_type(4))) float f32x4;
typedef __attribute__((ext_vector_type(8))) unsigned short u16x8;

#define KD 2304
#define PL 4232                      // padded plane stride (elems), multiple of 8
#define OUT_PER_B (256 * 1024)

static __device__ __forceinline__ ushort f2bf(float f) {
  union { float f; unsigned int i; } v; v.f = f;
  unsigned int x = v.i;
  x += 0x7fffu + ((x >> 16) & 1u);   // round-to-nearest-even
  return (ushort)(x >> 16);
}

#define GLDS16(gp, lp)                                                         \
  __builtin_amdgcn_global_load_lds(                                            \
      (const __attribute__((address_space(1))) void*)(gp),                     \
      (__attribute__((address_space(3))) void*)(lp), 16, 0, 0)

// swizzle: 16-B chunk g (0..15) of row r -> XOR low 3 bits with r&7 (involution)
#define SWZ(g, r) (((g) & 8) | (((g) ^ (r)) & 7))

// ---------------- Kernel 1: separable 4x4 FIR + weight cast ---------------------
__global__ __launch_bounds__(256) void k_fir(const float* __restrict__ x,
                                             ushort* __restrict__ xfn,
                                             const float* __restrict__ w,
                                             ushort* __restrict__ wb) {
  __shared__ float sxp[64 * 76];   // row r at cols 4..67; cols 2,3,68,69 zero halo
  __shared__ float stp[68 * 68];   // h-row i' at row i'+2; rows 0,1,66,67 zero
  const int plane = blockIdx.x;               // 0..4095
  const float* xp = x + (size_t)plane * 4096;
  ushort* op = xfn + (size_t)plane * PL;
  const int t = threadIdx.x;

  if (plane < 2304) {              // fused weight cast
    int iw = plane * 256 + t;
    float v = w[iw];
    int j = iw % 9;
    int t2 = iw / 9;
    int ic = t2 & 255;
    int oc = t2 >> 8;
    wb[oc * KD + j * 256 + ic] = f2bf(v);
  }

  {
    int r = t & 63, cs = t >> 6;
    int col = (cs < 2) ? (2 + cs) : (66 + cs);   // 2,3,68,69
    sxp[r * 76 + col] = 0.f;
  }
  for (int i = t; i < 272; i += 256) {           // 4 rows x 68
    int rr = i / 68, cc = i - rr * 68;
    int row = (rr < 2) ? rr : (64 + rr);         // 0,1,66,67
    stp[row * 68 + cc] = 0.f;
  }

  const float4* x4 = (const float4*)xp;
#pragma unroll
  for (int i = 0; i < 4; ++i) {
    int f4 = t + 256 * i;
    int r = f4 >> 4, w4 = f4 & 15;
    *(float4*)&sxp[r * 76 + 4 + w4 * 4] = x4[f4];
  }
  __syncthreads();

  for (int g = t; g < 1088; g += 256) {
    int i = g / 17, jg = g - i * 17;
    int j0 = jg << 2;
    const float* s = &sxp[i * 76 + j0];
    float4 a0 = *(const float4*)(s);
    float4 a1 = *(const float4*)(s + 4);
    float4 a2 = *(const float4*)(s + 8);
    float4 o;
    o.x = (a0.z + a1.y) + 3.f * (a0.w + a1.x);
    o.y = (a0.w + a1.z) + 3.f * (a1.x + a1.y);
    o.z = (a1.x + a1.w) + 3.f * (a1.y + a1.z);
    o.w = (a1.y + a2.x) + 3.f * (a1.z + a1.w);
    *(float4*)&stp[(i + 2) * 68 + j0] = o;
  }
  __syncthreads();

  for (int g = t; g < 1105; g += 256) {
    int i = g / 17, jg = g - i * 17;
    int j0 = jg << 2;
    const float* s = &stp[i * 68 + j0];
    float4 r0 = *(const float4*)(s);
    float4 r1 = *(const float4*)(s + 68);
    float4 r2 = *(const float4*)(s + 136);
    float4 r3 = *(const float4*)(s + 204);
    float4 o;
    o.x = (r0.x + r3.x) + 3.f * (r1.x + r2.x);
    o.y = (r0.y + r3.y) + 3.f * (r1.y + r2.y);
    o.z = (r0.z + r3.z) + 3.f * (r1.z + r2.z);
    o.w = (r0.w + r3.w) + 3.f * (r1.w + r2.w);
    ushort* q = op + i * 65 + j0;
    q[0] = f2bf(o.x * 0.015625f);
    if (j0 + 1 < 65) q[1] = f2bf(o.y * 0.015625f);
    if (j0 + 2 < 65) q[2] = f2bf(o.z * 0.015625f);
    if (j0 + 3 < 65) q[3] = f2bf(o.w * 0.015625f);
  }
}

// ---------------- Kernel 2: transpose NCHW -> NHWC (bf16), 16B both sides -------
__global__ __launch_bounds__(256) void k_tr(const ushort* __restrict__ xfn,
                                            ushort* __restrict__ xft) {
  __shared__ ushort ld[128 * 66];
  const int hw0 = blockIdx.x * 128;
  const int c0 = blockIdx.y * 64;
  const int b = blockIdx.z;
  const int t = threadIdx.x;

#pragma unroll
  for (int it = 0; it < 4; ++it) {
    int idx = it * 256 + t;                 // 0..1023
    int c = idx >> 4, q = idx & 15;
    u16x8 v = {};
    if (hw0 + q * 8 < 4225)
      v = *(const u16x8*)(xfn + (size_t)(b * 256 + c0 + c) * PL + hw0 + q * 8);
#pragma unroll
    for (int k = 0; k < 8; ++k)
      ld[(q * 8 + k) * 66 + (c ^ (k << 3))] = v[k];
  }
  __syncthreads();
#pragma unroll
  for (int it = 0; it < 4; ++it) {
    int idx = it * 256 + t;
    int hwl = idx >> 3, a = idx & 7;
    int k7 = hwl & 7;
    int hw = hw0 + hwl;
    if (hw < 4225) {
      u16x8 v = *(const u16x8*)&ld[hwl * 66 + ((a ^ k7) << 3)];
      *(u16x8*)&xft[((size_t)(b * 4225 + hw) << 8) + c0 + (a << 3)] = v;
    }
  }
}

// ---------------- Kernel 3: implicit-conv GEMM, split-K 8-wave ------------------
// C[oc=256][n=16384]; BM=128, BN=128, BK=128; 512 thr = 8 waves (2/SIMD).
// Wave (grp, wm, wn): quadrant (wm,wn) 64x64, K-group grp computes K-half
// [grp*64, grp*64+64) of each staged tile. Simple 2-barrier loop (compiler-
// managed drains), 18 iters. End: grp1 acc -> LDS -> grp0 adds + stores.
__global__ __launch_bounds__(512) void k_gemm3(const ushort* __restrict__ Wb,
                                               const ushort* __restrict__ Xt,
                                               const float* __restrict__ bias,
                                               float* __restrict__ out) {
  __shared__ ushort lds[2 * 128 * 128];            // 64 KB: lA | lB
  ushort* lA = lds;
  ushort* lB = lds + 128 * 128;
  const int bid = blockIdx.x;                      // 0..255
  const int work = (bid & 7) * 32 + (bid >> 3);    // XCD-chunked bijective
  const int ntile = work >> 1;
  const int mtile = work & 1;
  const int m0 = mtile * 128;
  const int n0 = ntile * 128;
  const int t = threadIdx.x;
  const int wid = t >> 6, lane = t & 63;
  const int grp = wid >> 2;                        // K-split group 0/1
  const int wm = (wid >> 1) & 1, wn = wid & 1;     // quadrant
  const int lrow = lane & 15, kgrp = lane >> 4;

  // staging sources (pre-swizzled; linear LDS dest idx*16B)
  const ushort* aB[4];
  const ushort* bB[4];
#pragma unroll
  for (int i = 0; i < 4; ++i) {
    int idx = i * 512 + t;                         // 0..2047
    int row = idx >> 4, g = idx & 15;
    aB[i] = Wb + (size_t)(m0 + row) * KD + SWZ(g, row) * 8;
    int n = n0 + row;
    int b = n >> 10, oh = (n >> 5) & 31, ow = n & 31;
    bB[i] = Xt + ((size_t)((b * 65 + 2 * oh) * 65 + 2 * ow) << 8) + SWZ(g, row) * 8;
  }

#define STAGE(st)                                                              \
  {                                                                            \
    const int j_ = (st) >> 1;                                                  \
    const int dh_ = j_ / 3, dw_ = j_ - 3 * dh_;                                \
    const int boff_ = (dh_ * 65 + dw_) * 256 + (((st) & 1) << 7);              \
    const int k0_ = (st) << 7;                                                 \
    _Pragma("unroll") for (int i_ = 0; i_ < 4; ++i_)                           \
        GLDS16(aB[i_] + k0_, &lA[(i_ * 512 + t) * 8]);                         \
    _Pragma("unroll") for (int i_ = 0; i_ < 4; ++i_)                           \
        GLDS16(bB[i_] + boff_, &lB[(i_ * 512 + t) * 8]);                       \
  }

  // fragment read offsets (ushort idx), static per thread
  int aOff[2][4], bOff[2][4];
#pragma unroll
  for (int f = 0; f < 4; ++f) {
#pragma unroll
    for (int s = 0; s < 2; ++s) {
      int gA = grp * 8 + s * 4 + kgrp;
      int arow = wm * 64 + f * 16 + lrow;
      int brow = wn * 64 + f * 16 + lrow;
      aOff[s][f] = arow * 128 + SWZ(gA, arow) * 8;
      bOff[s][f] = brow * 128 + SWZ(gA, brow) * 8;
    }
  }

  f32x4 acc[4][4];
#pragma unroll
  for (int i = 0; i < 4; ++i)
#pragma unroll
    for (int j = 0; j < 4; ++j) acc[i][j] = (f32x4){0.f, 0.f, 0.f, 0.f};

  for (int st = 0; st < 18; ++st) {
    __syncthreads();                 // previous compute done; buffers free
    STAGE(st);
    __syncthreads();                 // staged data resident (compiler drains)
#pragma unroll
    for (int s = 0; s < 2; ++s) {
      bf16x8 Af[4], Bf[4];
#pragma unroll
      for (int f = 0; f < 4; ++f) {
        Af[f] = *(const bf16x8*)&lA[aOff[s][f]];
        Bf[f] = *(const bf16x8*)&lB[bOff[s][f]];
      }
#pragma unroll
      for (int fm = 0; fm < 4; ++fm)
#pragma unroll
        for (int fn = 0; fn < 4; ++fn)
          acc[fm][fn] = __builtin_amdgcn_mfma_f32_16x16x32_bf16(
              Af[fm], Bf[fn], acc[fm][fn], 0, 0, 0);
    }
  }

  // split-K reduction: grp1 -> LDS, grp0 adds + stores
  __syncthreads();
  float* rbase = (float*)lds + (wm * 2 + wn) * 4096;   // 16 KB per quadrant
  if (grp == 1) {
#pragma unroll
    for (int fm = 0; fm < 4; ++fm)
#pragma unroll
      for (int fn = 0; fn < 4; ++fn)
        *(f32x4*)&rbase[(fm * 4 + fn) * 256 + lane * 4] = acc[fm][fn];
  }
  __syncthreads();
  if (grp == 0) {
    f32x4 bv[4];
#pragma unroll
    for (int fm = 0; fm < 4; ++fm)
      bv[fm] = *(const f32x4*)(bias + m0 + wm * 64 + fm * 16 + kgrp * 4);
#pragma unroll
    for (int fm = 0; fm < 4; ++fm) {
#pragma unroll
      for (int fn = 0; fn < 4; ++fn) {
        f32x4 other = *(const f32x4*)&rbase[(fm * 4 + fn) * 256 + lane * 4];
        f32x4 r = acc[fm][fn] + other;
        int nn = n0 + wn * 64 + fn * 16 + lrow;
        int oc = m0 + wm * 64 + fm * 16 + kgrp * 4;
        float* op = out + (size_t)(nn >> 10) * OUT_PER_B + (nn & 1023) +
                    (size_t)oc * 1024;
        op[0]    = r[0] + bv[fm][0];
        op[1024] = r[1] + bv[fm][1];
        op[2048] = r[2] + bv[fm][2];
        op[3072] = r[3] + bv[fm][3];
      }
    }
  }
}

extern "C" void kernel_launch(void* const* d_in, const int* in_sizes, int n_in,
                              void* d_out, int out_size, void* d_ws, size_t ws_size,
                              hipStream_t stream) {
  const float* x    = (const float*)d_in[0];  // [16,256,64,64]
  const float* w    = (const float*)d_in[1];  // [256,256,3,3]
  const float* bias = (const float*)d_in[2];  // [256]
  float* out = (float*)d_out;                 // [16,256,32,32]

  char* ws = (char*)d_ws;
  ushort* xfn = (ushort*)ws;                        // 4096*4232*2 = 34,668,544 B
  ushort* xft = (ushort*)(ws + 34668544);           // 16*4225*256*2 = 34,611,200 B
  ushort* wb  = (ushort*)(ws + 34668544 + 34611200);// 1,179,648 B

  k_fir<<<4096, 256, 0, stream>>>(x, xfn, w, wb);
  k_tr<<<dim3(34, 4, 16), 256, 0, stream>>>(xfn, xft);
  k_gemm3<<<256, 512, 0, stream>>>(wb, xft, bias, out);
}

// Round 12
// 71.841 us; speedup vs baseline: 1.2788x; 1.0497x over previous
//
#include <hip/hip_runtime.h>
#include <hip/hip_bf16.h>

typedef __attribute__((ext_vector_type(8))) short bf16x8;
typedef __attribute__((ext_vector_type(4))) float f32x4;
typedef __attribute__((ext_vector_type(8))) unsigned short u16x8;

#define KD 2304
#define OUT_PER_B (256 * 1024)

static __device__ __forceinline__ ushort f2bf(float f) {
  union { float f; unsigned int i; } v; v.f = f;
  unsigned int x = v.i;
  x += 0x7fffu + ((x >> 16) & 1u);   // round-to-nearest-even
  return (ushort)(x >> 16);
}
static __device__ __forceinline__ float bf2f(ushort u) {
  union { unsigned int i; float f; } v; v.i = ((unsigned)u) << 16; return v.f;
}

#define GLDS16(gp, lp)                                                         \
  __builtin_amdgcn_global_load_lds(                                            \
      (const __attribute__((address_space(1))) void*)(gp),                     \
      (__attribute__((address_space(3))) void*)(lp), 16, 0, 0)

// swizzle: 16-B chunk g (0..15) of row r -> XOR low 3 bits with r&7 (involution)
#define SWZ(g, r) (((g) & 8) | (((g) ^ (r)) & 7))

// ---------------- Kernel 1: fused FIR + NHWC transpose + weight cast ------------
// block = (13-row band, 64-ch group, batch); streaming row pipeline:
//   per input row ir: load->reg | v-emit o=ir-2 from ring | reg->sx | bar |
//                     h-filter ir -> ring[ir&3] | bar
// sx[64][76] f32 (halo cols 2,3,68,69 zero); ring[4][65][72] bf16.
__global__ __launch_bounds__(256) void k_fir2(const float* __restrict__ x,
                                              ushort* __restrict__ xft,
                                              const float* __restrict__ wsrc,
                                              ushort* __restrict__ wb) {
  __shared__ float sx[64 * 76];            // 19,456 B
  __shared__ ushort ring[4 * 65 * 72];     // 37,440 B
  const int band = blockIdx.x;             // 0..4
  const int c0 = blockIdx.y * 64;          // 0..3 -> ch group
  const int b = blockIdx.z;                // 0..15
  const int r0 = band * 13;
  const int t = threadIdx.x;

  // fused weight cast, grid-stride over 589824 elems (320 blocks x 256 thr)
  {
    int flat = band + 5 * (blockIdx.y + 4 * b);
    for (int iw = flat * 256 + t; iw < 589824; iw += 81920) {
      float v = wsrc[iw];
      int j = iw % 9;
      int t2 = iw / 9;
      int ic = t2 & 255, oc = t2 >> 8;
      wb[oc * KD + j * 256 + ic] = f2bf(v);
    }
  }

  // zero sx halo cols {2,3,68,69} (exactly 256 writes)
  {
    int r = t >> 2, cs = t & 3;
    sx[r * 76 + (cs < 2 ? 2 + cs : 66 + cs)] = 0.f;
  }

  for (int it = 0; it < 17; ++it) {
    const int ir = r0 - 2 + it;

    // (a) issue next staged row loads early (hide under v-emit)
    float4 rg[4];
    if (it <= 15) {
      if (ir >= 0 && ir < 64) {
#pragma unroll
        for (int i = 0; i < 4; ++i) {
          int f4 = i * 256 + t;
          int c = f4 >> 4, q = f4 & 15;
          rg[i] = *(const float4*)(x +
                    ((size_t)((b * 256 + c0 + c) * 64 + ir) << 6) + q * 4);
        }
      } else {
#pragma unroll
        for (int i = 0; i < 4; ++i) rg[i] = make_float4(0.f, 0.f, 0.f, 0.f);
      }
    }

    // (b) v-emit output row o = ir - 2 (uses h[o-2..o+1] = ring, pre-overwrite)
    if (it >= 4) {
      const int o = r0 - 4 + it;
#pragma unroll
      for (int i2 = 0; i2 < 3; ++i2) {
        int idx = i2 * 256 + t;
        if (idx < 520) {
          int w = idx >> 3, a = idx & 7;
          u16x8 r4[4];
#pragma unroll
          for (int d = 0; d < 4; ++d) {
            int slot = (o - 2 + d) & 3;
            r4[d] = *(const u16x8*)&ring[(slot * 65 + w) * 72 + a * 8];
          }
          u16x8 ov;
#pragma unroll
          for (int k = 0; k < 8; ++k) {
            float f0 = bf2f(r4[0][k]), f1 = bf2f(r4[1][k]);
            float f2 = bf2f(r4[2][k]), f3 = bf2f(r4[3][k]);
            ov[k] = f2bf(((f0 + f3) + 3.f * (f1 + f2)) * 0.015625f);
          }
          *(u16x8*)&xft[((size_t)(b * 4225 + o * 65 + w) << 8) + c0 + a * 8] = ov;
        }
      }
    }

    // (c) staged row regs -> sx
    if (it <= 15) {
#pragma unroll
      for (int i = 0; i < 4; ++i) {
        int f4 = i * 256 + t;
        int c = f4 >> 4, q = f4 & 15;
        *(float4*)&sx[c * 76 + 4 + q * 4] = rg[i];
      }
    }
    __syncthreads();

    // (d) h-filter row ir -> ring[ir&3]
    if (it <= 15) {
      ushort* rw = ring + (ir & 3) * 65 * 72;
#pragma unroll
      for (int i2 = 0; i2 < 5; ++i2) {
        int idx = i2 * 256 + t;
        if (idx < 1088) {
          int g = idx >> 6, c = idx & 63;
          const float* s = &sx[c * 76 + g * 4];
          float4 a0 = *(const float4*)(s);
          float4 a1 = *(const float4*)(s + 4);
          float4 a2 = *(const float4*)(s + 8);
          int w0 = g * 4;
          rw[w0 * 72 + c] = f2bf((a0.z + a1.y) + 3.f * (a0.w + a1.x));
          if (w0 + 1 < 65) rw[(w0 + 1) * 72 + c] = f2bf((a0.w + a1.z) + 3.f * (a1.x + a1.y));
          if (w0 + 2 < 65) rw[(w0 + 2) * 72 + c] = f2bf((a1.x + a1.w) + 3.f * (a1.y + a1.z));
          if (w0 + 3 < 65) rw[(w0 + 3) * 72 + c] = f2bf((a1.y + a2.x) + 3.f * (a1.z + a1.w));
        }
      }
    }
    __syncthreads();
  }
}

// ---------------- Kernel 2: implicit-conv GEMM (R7 proven), BK=128 --------------
// C[oc=256][n=16384]; BM=128, BN=64, BK=128; 256 thr (4 waves 2m x 2n, 64x32 each)
__global__ __launch_bounds__(256) void k_gemm3(const ushort* __restrict__ Wb,
                                               const ushort* __restrict__ Xt,
                                               const float* __restrict__ bias,
                                               float* __restrict__ out) {
  __shared__ ushort lA[128 * 128];                 // 32 KB
  __shared__ ushort lB[64 * 128];                  // 16 KB
  const int bid = blockIdx.x;                      // 0..511
  const int work = (bid & 7) * 64 + (bid >> 3);    // XCD-chunked bijective
  const int ntile = work >> 1;
  const int mtile = work & 1;
  const int m0 = mtile * 128;
  const int n0 = ntile * 64;
  const int t = threadIdx.x;
  const int wid = t >> 6, lane = t & 63;
  const int wm = wid >> 1, wn = wid & 1;
  const int lrow = lane & 15, kgrp = lane >> 4;

  const ushort* aB[8];
#pragma unroll
  for (int i = 0; i < 8; ++i) {
    int idx = i * 256 + t;
    int row = idx >> 4, gL = idx & 15;
    aB[i] = Wb + (size_t)(m0 + row) * KD + SWZ(gL, row) * 8;
  }
  const ushort* bB[4];
#pragma unroll
  for (int i = 0; i < 4; ++i) {
    int idx = i * 256 + t;
    int row = idx >> 4, gL = idx & 15;
    int n = n0 + row;
    int b = n >> 10, oh = (n >> 5) & 31, ow = n & 31;
    bB[i] = Xt + ((size_t)((b * 65 + 2 * oh) * 65 + 2 * ow) << 8) +
            SWZ(gL, row) * 8;
  }

  f32x4 acc[4][2];
#pragma unroll
  for (int i = 0; i < 4; ++i)
#pragma unroll
    for (int j = 0; j < 2; ++j) acc[i][j] = (f32x4){0.f, 0.f, 0.f, 0.f};

  for (int kt = 0; kt < 18; ++kt) {
    const int j = kt >> 1;
    const int dh = j / 3, dw = j - 3 * dh;
    const int boff = (dh * 65 + dw) * 256 + ((kt & 1) << 7);
    const int k0 = kt << 7;
    __syncthreads();
#pragma unroll
    for (int i = 0; i < 8; ++i)
      GLDS16(aB[i] + k0, &lA[(i * 256 + t) * 8]);
#pragma unroll
    for (int i = 0; i < 4; ++i)
      GLDS16(bB[i] + boff, &lB[(i * 256 + t) * 8]);
    __syncthreads();

#pragma unroll
    for (int s = 0; s < 4; ++s) {
      bf16x8 Af[4], Bf[2];
#pragma unroll
      for (int f = 0; f < 4; ++f) {
        int row = wm * 64 + f * 16 + lrow;
        Af[f] = *(const bf16x8*)&lA[row * 128 + SWZ(s * 4 + kgrp, row) * 8];
      }
#pragma unroll
      for (int f = 0; f < 2; ++f) {
        int row = wn * 32 + f * 16 + lrow;
        Bf[f] = *(const bf16x8*)&lB[row * 128 + SWZ(s * 4 + kgrp, row) * 8];
      }
#pragma unroll
      for (int fm = 0; fm < 4; ++fm)
#pragma unroll
        for (int fn = 0; fn < 2; ++fn)
          acc[fm][fn] = __builtin_amdgcn_mfma_f32_16x16x32_bf16(
              Af[fm], Bf[fn], acc[fm][fn], 0, 0, 0);
    }
  }

  f32x4 bv[4];
#pragma unroll
  for (int fm = 0; fm < 4; ++fm)
    bv[fm] = *(const f32x4*)(bias + m0 + wm * 64 + fm * 16 + kgrp * 4);

#pragma unroll
  for (int fm = 0; fm < 4; ++fm) {
#pragma unroll
    for (int fn = 0; fn < 2; ++fn) {
      int nn = n0 + wn * 32 + fn * 16 + lrow;
      int oc = m0 + wm * 64 + fm * 16 + kgrp * 4;
      float* op = out + (size_t)(nn >> 10) * OUT_PER_B + (nn & 1023) +
                  (size_t)oc * 1024;
      op[0]    = acc[fm][fn][0] + bv[fm][0];
      op[1024] = acc[fm][fn][1] + bv[fm][1];
      op[2048] = acc[fm][fn][2] + bv[fm][2];
      op[3072] = acc[fm][fn][3] + bv[fm][3];
    }
  }
}

extern "C" void kernel_launch(void* const* d_in, const int* in_sizes, int n_in,
                              void* d_out, int out_size, void* d_ws, size_t ws_size,
                              hipStream_t stream) {
  const float* x    = (const float*)d_in[0];  // [16,256,64,64]
  const float* w    = (const float*)d_in[1];  // [256,256,3,3]
  const float* bias = (const float*)d_in[2];  // [256]
  float* out = (float*)d_out;                 // [16,256,32,32]

  char* ws = (char*)d_ws;
  ushort* xft = (ushort*)ws;                        // 16*4225*256*2 = 34,611,200 B
  ushort* wb  = (ushort*)(ws + 34611200);           // 1,179,648 B

  k_fir2<<<dim3(5, 4, 16), 256, 0, stream>>>(x, xft, w, wb);
  k_gemm3<<<512, 256, 0, stream>>>(wb, xft, bias, out);
}

// Round 13
// 68.151 us; speedup vs baseline: 1.3480x; 1.0542x over previous
//
#include <hip/hip_runtime.h>
#include <hip/hip_bf16.h>

typedef __attribute__((ext_vector_type(8))) short bf16x8;
typedef __attribute__((ext_vector_type(4))) float f32x4;
typedef __attribute__((ext_vector_type(8))) unsigned short u16x8;

#define KD 2304
#define OUT_PER_B (256 * 1024)

static __device__ __forceinline__ ushort f2bf(float f) {
  union { float f; unsigned int i; } v; v.f = f;
  unsigned int x = v.i;
  x += 0x7fffu + ((x >> 16) & 1u);   // round-to-nearest-even
  return (ushort)(x >> 16);
}
static __device__ __forceinline__ float bf2f(ushort u) {
  union { unsigned int i; float f; } v; v.i = ((unsigned)u) << 16; return v.f;
}

#define GLDS16(gp, lp)                                                         \
  __builtin_amdgcn_global_load_lds(                                            \
      (const __attribute__((address_space(1))) void*)(gp),                     \
      (__attribute__((address_space(3))) void*)(lp), 16, 0, 0)

// swizzle: 16-B chunk g (0..15) of row r -> XOR low 3 bits with r&7 (involution)
#define SWZ(g, r) (((g) & 8) | (((g) ^ (r)) & 7))

// ---------------- Kernel 1: fused FIR + NHWC + weight cast (occupancy fix) ------
// block = (13-row band, 32-ch group, batch) = 640 blocks, ~28 KB LDS -> 2.5/CU.
// sx[32][84] f32 (stride 21 dwords, odd -> conflict-free); ring[4][65][34] bf16
// (stride 17 dwords, odd -> v-emit b128 reads spread across banks).
__global__ __launch_bounds__(256) void k_fir3(const float* __restrict__ x,
                                              ushort* __restrict__ xft,
                                              const float* __restrict__ wsrc,
                                              ushort* __restrict__ wb) {
  __shared__ float sx[32 * 84];            // 10,752 B; row c data at cols 4..67
  __shared__ ushort ring[4 * 65 * 34];     // 17,680 B; [slot][w][c]
  const int band = blockIdx.x;             // 0..4  (13 output rows each)
  const int c0 = blockIdx.y * 32;          // 8 ch groups
  const int b = blockIdx.z;                // 16
  const int r0 = band * 13;
  const int t = threadIdx.x;

  // fused weight cast, grid-stride (640 blocks x 256 thr = 163840)
  {
    int flat = band + 5 * (blockIdx.y + 8 * b);
    for (int iw = flat * 256 + t; iw < 589824; iw += 163840) {
      float v = wsrc[iw];
      int j = iw % 9;
      int t2 = iw / 9;
      int ic = t2 & 255, oc = t2 >> 8;
      wb[oc * KD + j * 256 + ic] = f2bf(v);
    }
  }

  // zero sx halo cols {2,3,68,69}: 32 rows x 4 = 128 writes
  if (t < 128) {
    int r = t >> 2, cs = t & 3;
    sx[r * 84 + (cs < 2 ? 2 + cs : 66 + cs)] = 0.f;
  }

  for (int it = 0; it < 17; ++it) {
    const int ir = r0 - 2 + it;

    // (a) issue next input row loads early (32 ch x 16 f4 = 512 -> 2/thread)
    float4 rg[2];
    if (it <= 15) {
      if (ir >= 0 && ir < 64) {
#pragma unroll
        for (int i = 0; i < 2; ++i) {
          int f4 = i * 256 + t;
          int c = f4 >> 4, q = f4 & 15;
          rg[i] = *(const float4*)(x +
                    ((size_t)((b * 256 + c0 + c) * 64 + ir) << 6) + q * 4);
        }
      } else {
        rg[0] = rg[1] = make_float4(0.f, 0.f, 0.f, 0.f);
      }
    }

    // (b) v-emit output row o = ir - 2 from ring (h[o-2..o+1]); 65 w x 4 chunks
    if (it >= 4) {
      const int o = r0 - 4 + it;
      for (int idx = t; idx < 260; idx += 256) {
        int w = idx >> 2, a = idx & 3;
        u16x8 r4[4];
#pragma unroll
        for (int d = 0; d < 4; ++d) {
          int slot = (o - 2 + d) & 3;
          r4[d] = *(const u16x8*)&ring[(slot * 65 + w) * 34 + a * 8];
        }
        u16x8 ov;
#pragma unroll
        for (int k = 0; k < 8; ++k) {
          float f0 = bf2f(r4[0][k]), f1 = bf2f(r4[1][k]);
          float f2 = bf2f(r4[2][k]), f3 = bf2f(r4[3][k]);
          ov[k] = f2bf(((f0 + f3) + 3.f * (f1 + f2)) * 0.015625f);
        }
        *(u16x8*)&xft[((size_t)(b * 4225 + o * 65 + w) << 8) + c0 + a * 8] = ov;
      }
    }

    // (c) staged row regs -> sx
    if (it <= 15) {
#pragma unroll
      for (int i = 0; i < 2; ++i) {
        int f4 = i * 256 + t;
        int c = f4 >> 4, q = f4 & 15;
        *(float4*)&sx[c * 84 + 4 + q * 4] = rg[i];
      }
    }
    __syncthreads();

    // (d) h-filter row ir -> ring[ir&3]; 17 w-groups x 32 c = 544 items
    if (it <= 15) {
      ushort* rw = ring + (ir & 3) * 65 * 34;
      for (int idx = t; idx < 544; idx += 256) {
        int g = idx >> 5, c = idx & 31;
        const float* s = &sx[c * 84 + g * 4];
        float4 a0 = *(const float4*)(s);
        float4 a1 = *(const float4*)(s + 4);
        float4 a2 = *(const float4*)(s + 8);
        int w0 = g * 4;
        rw[w0 * 34 + c] = f2bf((a0.z + a1.y) + 3.f * (a0.w + a1.x));
        if (w0 + 1 < 65) rw[(w0 + 1) * 34 + c] = f2bf((a0.w + a1.z) + 3.f * (a1.x + a1.y));
        if (w0 + 2 < 65) rw[(w0 + 2) * 34 + c] = f2bf((a1.x + a1.w) + 3.f * (a1.y + a1.z));
        if (w0 + 3 < 65) rw[(w0 + 3) * 34 + c] = f2bf((a1.y + a2.x) + 3.f * (a1.z + a1.w));
      }
    }
    __syncthreads();
  }
}

// ---------------- Kernel 2: implicit-conv GEMM (proven), BK=128 -----------------
// C[oc=256][n=16384]; BM=128, BN=64, BK=128; 256 thr (4 waves 2m x 2n, 64x32 each)
__global__ __launch_bounds__(256) void k_gemm3(const ushort* __restrict__ Wb,
                                               const ushort* __restrict__ Xt,
                                               const float* __restrict__ bias,
                                               float* __restrict__ out) {
  __shared__ ushort lA[128 * 128];                 // 32 KB
  __shared__ ushort lB[64 * 128];                  // 16 KB
  const int bid = blockIdx.x;                      // 0..511
  const int work = (bid & 7) * 64 + (bid >> 3);    // XCD-chunked bijective
  const int ntile = work >> 1;
  const int mtile = work & 1;
  const int m0 = mtile * 128;
  const int n0 = ntile * 64;
  const int t = threadIdx.x;
  const int wid = t >> 6, lane = t & 63;
  const int wm = wid >> 1, wn = wid & 1;
  const int lrow = lane & 15, kgrp = lane >> 4;

  const ushort* aB[8];
#pragma unroll
  for (int i = 0; i < 8; ++i) {
    int idx = i * 256 + t;
    int row = idx >> 4, gL = idx & 15;
    aB[i] = Wb + (size_t)(m0 + row) * KD + SWZ(gL, row) * 8;
  }
  const ushort* bB[4];
#pragma unroll
  for (int i = 0; i < 4; ++i) {
    int idx = i * 256 + t;
    int row = idx >> 4, gL = idx & 15;
    int n = n0 + row;
    int b = n >> 10, oh = (n >> 5) & 31, ow = n & 31;
    bB[i] = Xt + ((size_t)((b * 65 + 2 * oh) * 65 + 2 * ow) << 8) +
            SWZ(gL, row) * 8;
  }

  f32x4 acc[4][2];
#pragma unroll
  for (int i = 0; i < 4; ++i)
#pragma unroll
    for (int j = 0; j < 2; ++j) acc[i][j] = (f32x4){0.f, 0.f, 0.f, 0.f};

  for (int kt = 0; kt < 18; ++kt) {
    const int j = kt >> 1;
    const int dh = j / 3, dw = j - 3 * dh;
    const int boff = (dh * 65 + dw) * 256 + ((kt & 1) << 7);
    const int k0 = kt << 7;
    __syncthreads();
#pragma unroll
    for (int i = 0; i < 8; ++i)
      GLDS16(aB[i] + k0, &lA[(i * 256 + t) * 8]);
#pragma unroll
    for (int i = 0; i < 4; ++i)
      GLDS16(bB[i] + boff, &lB[(i * 256 + t) * 8]);
    __syncthreads();

#pragma unroll
    for (int s = 0; s < 4; ++s) {
      bf16x8 Af[4], Bf[2];
#pragma unroll
      for (int f = 0; f < 4; ++f) {
        int row = wm * 64 + f * 16 + lrow;
        Af[f] = *(const bf16x8*)&lA[row * 128 + SWZ(s * 4 + kgrp, row) * 8];
      }
#pragma unroll
      for (int f = 0; f < 2; ++f) {
        int row = wn * 32 + f * 16 + lrow;
        Bf[f] = *(const bf16x8*)&lB[row * 128 + SWZ(s * 4 + kgrp, row) * 8];
      }
#pragma unroll
      for (int fm = 0; fm < 4; ++fm)
#pragma unroll
        for (int fn = 0; fn < 2; ++fn)
          acc[fm][fn] = __builtin_amdgcn_mfma_f32_16x16x32_bf16(
              Af[fm], Bf[fn], acc[fm][fn], 0, 0, 0);
    }
  }

  f32x4 bv[4];
#pragma unroll
  for (int fm = 0; fm < 4; ++fm)
    bv[fm] = *(const f32x4*)(bias + m0 + wm * 64 + fm * 16 + kgrp * 4);

#pragma unroll
  for (int fm = 0; fm < 4; ++fm) {
#pragma unroll
    for (int fn = 0; fn < 2; ++fn) {
      int nn = n0 + wn * 32 + fn * 16 + lrow;
      int oc = m0 + wm * 64 + fm * 16 + kgrp * 4;
      float* op = out + (size_t)(nn >> 10) * OUT_PER_B + (nn & 1023) +
                  (size_t)oc * 1024;
      op[0]    = acc[fm][fn][0] + bv[fm][0];
      op[1024] = acc[fm][fn][1] + bv[fm][1];
      op[2048] = acc[fm][fn][2] + bv[fm][2];
      op[3072] = acc[fm][fn][3] + bv[fm][3];
    }
  }
}

extern "C" void kernel_launch(void* const* d_in, const int* in_sizes, int n_in,
                              void* d_out, int out_size, void* d_ws, size_t ws_size,
                              hipStream_t stream) {
  const float* x    = (const float*)d_in[0];  // [16,256,64,64]
  const float* w    = (const float*)d_in[1];  // [256,256,3,3]
  const float* bias = (const float*)d_in[2];  // [256]
  float* out = (float*)d_out;                 // [16,256,32,32]

  char* ws = (char*)d_ws;
  ushort* xft = (ushort*)ws;                        // 16*4225*256*2 = 34,611,200 B
  ushort* wb  = (ushort*)(ws + 34611200);           // 1,179,648 B

  k_fir3<<<dim3(5, 8, 16), 256, 0, stream>>>(x, xft, w, wb);
  k_gemm3<<<512, 256, 0, stream>>>(wb, xft, bias, out);
}

// Round 14
// 67.562 us; speedup vs baseline: 1.3598x; 1.0087x over previous
//
#include <hip/hip_runtime.h>
#include <hip/hip_bf16.h>

typedef __attribute__((ext_vector_type(8))) short bf16x8;
typedef __attribute__((ext_vector_type(4))) float f32x4;
typedef __attribute__((ext_vector_type(8))) unsigned short u16x8;

#define KD 2304
#define OUT_PER_B (256 * 1024)

static __device__ __forceinline__ ushort f2bf(float f) {
  union { float f; unsigned int i; } v; v.f = f;
  unsigned int x = v.i;
  x += 0x7fffu + ((x >> 16) & 1u);   // round-to-nearest-even
  return (ushort)(x >> 16);
}
static __device__ __forceinline__ float bf2f(ushort u) {
  union { unsigned int i; float f; } v; v.i = ((unsigned)u) << 16; return v.f;
}

#define GLDS16(gp, lp)                                                         \
  __builtin_amdgcn_global_load_lds(                                            \
      (const __attribute__((address_space(1))) void*)(gp),                     \
      (__attribute__((address_space(3))) void*)(lp), 16, 0, 0)

// swizzle: 16-B chunk g (0..15) of row r -> XOR low 3 bits with r&7 (involution)
#define SWZ(g, r) (((g) & 8) | (((g) ^ (r)) & 7))

// ---------------- Kernel 1: fused FIR + NHWC + weight cast, WAVE-AUTONOMOUS -----
// wave = (13-row band, 8-channel octet): private sx[8][84] f32 + ring[4][65][8]
// bf16. No __syncthreads anywhere — all LDS dependencies are same-wave (in-order
// LDS pipeline + compiler lgkmcnt). 2560 independent waves, 10/CU.
__global__ __launch_bounds__(256) void k_fir4(const float* __restrict__ x,
                                              ushort* __restrict__ xft,
                                              const float* __restrict__ wsrc,
                                              ushort* __restrict__ wb) {
  __shared__ float sxAll[4][8 * 84];          // 10,752 B
  __shared__ ushort ringAll[4][4 * 65 * 8];   // 16,640 B  (27.4 KB total)
  const int band = blockIdx.x;                // 0..4 (13 output rows each)
  const int cg = blockIdx.y;                  // 0..7 (32-ch group)
  const int b = blockIdx.z;                   // 0..15
  const int t = threadIdx.x;
  const int wid = t >> 6, lane = t & 63;
  const int coct = cg * 32 + wid * 8;         // this wave's channel octet
  const int r0 = band * 13;
  float* sx = sxAll[wid];
  ushort* ring = ringAll[wid];

  // fused weight cast, grid-stride (640 blocks x 256 thr)
  {
    int flat = band + 5 * (cg + 8 * b);
    for (int iw = flat * 256 + t; iw < 589824; iw += 163840) {
      float v = wsrc[iw];
      int j = iw % 9;
      int t2 = iw / 9;
      int ic = t2 & 255, oc = t2 >> 8;
      wb[oc * KD + j * 256 + ic] = f2bf(v);
    }
  }

  // zero sx halo cols {2,3,68,69}: 8 rows x 4 (lanes < 32)
  if (lane < 32) {
    int r = lane >> 2, cs = lane & 3;
    sx[r * 84 + (cs < 2 ? 2 + cs : 66 + cs)] = 0.f;
  }

  for (int it = 0; it < 17; ++it) {
    const int ir = r0 - 2 + it;

    // (a) issue input row loads early: 8 ch x 16 f4 = 128 f4, 2/lane
    float4 rg0, rg1;
    if (it <= 15) {
      if (ir >= 0 && ir < 64) {
        rg0 = *(const float4*)(x +
              ((size_t)((b * 256 + coct + (lane >> 4)) * 64 + ir) << 6) +
              (lane & 15) * 4);
        rg1 = *(const float4*)(x +
              ((size_t)((b * 256 + coct + 4 + (lane >> 4)) * 64 + ir) << 6) +
              (lane & 15) * 4);
      } else {
        rg0 = rg1 = make_float4(0.f, 0.f, 0.f, 0.f);
      }
    }

    // (b) v-emit output row o = ir-2 from ring slots (o-2..o+1)&3
    if (it >= 4) {
      const int o = r0 - 4 + it;
      for (int w = lane; w < 65; w += 64) {
        u16x8 r4[4];
#pragma unroll
        for (int d = 0; d < 4; ++d) {
          int slot = (o - 2 + d) & 3;
          r4[d] = *(const u16x8*)&ring[(slot * 65 + w) * 8];
        }
        u16x8 ov;
#pragma unroll
        for (int k = 0; k < 8; ++k) {
          float f0 = bf2f(r4[0][k]), f1 = bf2f(r4[1][k]);
          float f2 = bf2f(r4[2][k]), f3 = bf2f(r4[3][k]);
          ov[k] = f2bf(((f0 + f3) + 3.f * (f1 + f2)) * 0.015625f);
        }
        *(u16x8*)&xft[((size_t)(b * 4225 + o * 65 + w) << 8) + coct] = ov;
      }
    }

    // (c) staged row -> sx (cols 4..67)
    if (it <= 15) {
      *(float4*)&sx[(lane >> 4) * 84 + 4 + (lane & 15) * 4] = rg0;
      *(float4*)&sx[(4 + (lane >> 4)) * 84 + 4 + (lane & 15) * 4] = rg1;
    }
    __builtin_amdgcn_wave_barrier();

    // (d) h-filter row ir -> ring[ir&3]: 17 w-groups x 8 c = 136 items
    if (it <= 15) {
      ushort* rw = ring + (ir & 3) * 65 * 8;
      for (int idx = lane; idx < 136; idx += 64) {
        int g = idx >> 3, c = idx & 7;
        const float* s = &sx[c * 84 + g * 4];
        float4 a0 = *(const float4*)(s);
        float4 a1 = *(const float4*)(s + 4);
        float4 a2 = *(const float4*)(s + 8);
        int w0 = g * 4;
        rw[w0 * 8 + c] = f2bf((a0.z + a1.y) + 3.f * (a0.w + a1.x));
        if (w0 + 1 < 65) rw[(w0 + 1) * 8 + c] = f2bf((a0.w + a1.z) + 3.f * (a1.x + a1.y));
        if (w0 + 2 < 65) rw[(w0 + 2) * 8 + c] = f2bf((a1.x + a1.w) + 3.f * (a1.y + a1.z));
        if (w0 + 3 < 65) rw[(w0 + 3) * 8 + c] = f2bf((a1.y + a2.x) + 3.f * (a1.z + a1.w));
      }
    }
    __builtin_amdgcn_wave_barrier();
  }
}

// ---------------- Kernel 2: implicit-conv GEMM (proven), BK=128 -----------------
// C[oc=256][n=16384]; BM=128, BN=64, BK=128; 256 thr (4 waves 2m x 2n, 64x32 each)
__global__ __launch_bounds__(256) void k_gemm3(const ushort* __restrict__ Wb,
                                               const ushort* __restrict__ Xt,
                                               const float* __restrict__ bias,
                                               float* __restrict__ out) {
  __shared__ ushort lA[128 * 128];                 // 32 KB
  __shared__ ushort lB[64 * 128];                  // 16 KB
  const int bid = blockIdx.x;                      // 0..511
  const int work = (bid & 7) * 64 + (bid >> 3);    // XCD-chunked bijective
  const int ntile = work >> 1;
  const int mtile = work & 1;
  const int m0 = mtile * 128;
  const int n0 = ntile * 64;
  const int t = threadIdx.x;
  const int wid = t >> 6, lane = t & 63;
  const int wm = wid >> 1, wn = wid & 1;
  const int lrow = lane & 15, kgrp = lane >> 4;

  const ushort* aB[8];
#pragma unroll
  for (int i = 0; i < 8; ++i) {
    int idx = i * 256 + t;
    int row = idx >> 4, gL = idx & 15;
    aB[i] = Wb + (size_t)(m0 + row) * KD + SWZ(gL, row) * 8;
  }
  const ushort* bB[4];
#pragma unroll
  for (int i = 0; i < 4; ++i) {
    int idx = i * 256 + t;
    int row = idx >> 4, gL = idx & 15;
    int n = n0 + row;
    int b = n >> 10, oh = (n >> 5) & 31, ow = n & 31;
    bB[i] = Xt + ((size_t)((b * 65 + 2 * oh) * 65 + 2 * ow) << 8) +
            SWZ(gL, row) * 8;
  }

  f32x4 acc[4][2];
#pragma unroll
  for (int i = 0; i < 4; ++i)
#pragma unroll
    for (int j = 0; j < 2; ++j) acc[i][j] = (f32x4){0.f, 0.f, 0.f, 0.f};

  for (int kt = 0; kt < 18; ++kt) {
    const int j = kt >> 1;
    const int dh = j / 3, dw = j - 3 * dh;
    const int boff = (dh * 65 + dw) * 256 + ((kt & 1) << 7);
    const int k0 = kt << 7;
    __syncthreads();
#pragma unroll
    for (int i = 0; i < 8; ++i)
      GLDS16(aB[i] + k0, &lA[(i * 256 + t) * 8]);
#pragma unroll
    for (int i = 0; i < 4; ++i)
      GLDS16(bB[i] + boff, &lB[(i * 256 + t) * 8]);
    __syncthreads();

#pragma unroll
    for (int s = 0; s < 4; ++s) {
      bf16x8 Af[4], Bf[2];
#pragma unroll
      for (int f = 0; f < 4; ++f) {
        int row = wm * 64 + f * 16 + lrow;
        Af[f] = *(const bf16x8*)&lA[row * 128 + SWZ(s * 4 + kgrp, row) * 8];
      }
#pragma unroll
      for (int f = 0; f < 2; ++f) {
        int row = wn * 32 + f * 16 + lrow;
        Bf[f] = *(const bf16x8*)&lB[row * 128 + SWZ(s * 4 + kgrp, row) * 8];
      }
#pragma unroll
      for (int fm = 0; fm < 4; ++fm)
#pragma unroll
        for (int fn = 0; fn < 2; ++fn)
          acc[fm][fn] = __builtin_amdgcn_mfma_f32_16x16x32_bf16(
              Af[fm], Bf[fn], acc[fm][fn], 0, 0, 0);
    }
  }

  f32x4 bv[4];
#pragma unroll
  for (int fm = 0; fm < 4; ++fm)
    bv[fm] = *(const f32x4*)(bias + m0 + wm * 64 + fm * 16 + kgrp * 4);

#pragma unroll
  for (int fm = 0; fm < 4; ++fm) {
#pragma unroll
    for (int fn = 0; fn < 2; ++fn) {
      int nn = n0 + wn * 32 + fn * 16 + lrow;
      int oc = m0 + wm * 64 + fm * 16 + kgrp * 4;
      float* op = out + (size_t)(nn >> 10) * OUT_PER_B + (nn & 1023) +
                  (size_t)oc * 1024;
      op[0]    = acc[fm][fn][0] + bv[fm][0];
      op[1024] = acc[fm][fn][1] + bv[fm][1];
      op[2048] = acc[fm][fn][2] + bv[fm][2];
      op[3072] = acc[fm][fn][3] + bv[fm][3];
    }
  }
}

extern "C" void kernel_launch(void* const* d_in, const int* in_sizes, int n_in,
                              void* d_out, int out_size, void* d_ws, size_t ws_size,
                              hipStream_t stream) {
  const float* x    = (const float*)d_in[0];  // [16,256,64,64]
  const float* w    = (const float*)d_in[1];  // [256,256,3,3]
  const float* bias = (const float*)d_in[2];  // [256]
  float* out = (float*)d_out;                 // [16,256,32,32]

  char* ws = (char*)d_ws;
  ushort* xft = (ushort*)ws;                        // 16*4225*256*2 = 34,611,200 B
  ushort* wb  = (ushort*)(ws + 34611200);           // 1,179,648 B

  k_fir4<<<dim3(5, 8, 16), 256, 0, stream>>>(x, xft, w, wb);
  k_gemm3<<<512, 256, 0, stream>>>(wb, xft, bias, out);
}

// Round 15
// 61.480 us; speedup vs baseline: 1.4943x; 1.0989x over previous
//
#include <hip/hip_runtime.h>
#include <hip/hip_bf16.h>

typedef __attribute__((ext_vector_type(8))) short bf16x8;
typedef __attribute__((ext_vector_type(4))) float f32x4;
typedef __attribute__((ext_vector_type(8))) unsigned short u16x8;

#define KD 2304
#define OUT_PER_B (256 * 1024)

static __device__ __forceinline__ ushort f2bf(float f) {
  union { float f; unsigned int i; } v; v.f = f;
  unsigned int x = v.i;
  x += 0x7fffu + ((x >> 16) & 1u);   // round-to-nearest-even
  return (ushort)(x >> 16);
}

#define GLDS16(gp, lp)                                                         \
  __builtin_amdgcn_global_load_lds(                                            \
      (const __attribute__((address_space(1))) void*)(gp),                     \
      (__attribute__((address_space(3))) void*)(lp), 16, 0, 0)

// swizzle: 16-B chunk g (0..15) of row r -> XOR low 3 bits with r&7 (involution)
#define SWZ(g, r) (((g) & 8) | (((g) ^ (r)) & 7))

#define CVTPK(d, lo, hi) \
  asm("v_cvt_pk_bf16_f32 %0, %1, %2" : "=v"(d) : "v"(lo), "v"(hi))

// ---------------- Kernel 1: fused FIR(v->h) + NHWC + weight cast ---------------
// Thread (c 0..7 within wave, o = w-octet 0..7). Vertical filter in a register
// ring (slot = row&7, h0 % 8 == 0 -> compile-time slots); horizontal filter via
// lane shuffles; LDS only for the 8x64 output transpose (per-wave, 1.3 KB).
// No __syncthreads. Grid (5 bands, 8 cg, 16 b); bands 0-3 = 16 rows, band 4 = 1.
__global__ __launch_bounds__(256) void k_fir5(const float* __restrict__ x,
                                              ushort* __restrict__ xft,
                                              const float* __restrict__ wsrc,
                                              ushort* __restrict__ wb) {
  __shared__ ushort stageAll[4][8 * 80];     // per-wave [c][80] ushorts
  const int band = blockIdx.x;               // 0..4; h0 = band*16
  const int cg = blockIdx.y;                 // 0..7
  const int b = blockIdx.z;                  // 0..15
  const int t = threadIdx.x;
  const int wid = t >> 6, lane = t & 63;
  const int c = lane >> 3, o = lane & 7;
  const int cw = cg * 32 + wid * 8;          // wave channel base
  const int h0 = band * 16;
  const int nrows = (band == 4) ? 1 : 16;
  ushort* stage = stageAll[wid];

  // fused weight cast, grid-stride (640 blocks x 256 thr)
  {
    int flat = band + 5 * (cg + 8 * b);
    for (int iw = flat * 256 + t; iw < 589824; iw += 163840) {
      float v = wsrc[iw];
      int j = iw % 9;
      int t2 = iw / 9;
      wb[(t2 >> 8) * KD + j * 256 + (t2 & 255)] = f2bf(v);
    }
  }

  const float* xrow = x + ((size_t)(b * 256 + cw + c) << 12) + o * 8;

  float4 rA[8], rB[8];
#define LOADR(s, r)                                                            \
  {                                                                            \
    if ((unsigned)(r) < 64u) {                                                 \
      rA[s] = *(const float4*)(xrow + (r) * 64);                               \
      rB[s] = *(const float4*)(xrow + (r) * 64 + 4);                           \
    } else {                                                                   \
      rA[s] = make_float4(0.f, 0.f, 0.f, 0.f);                                 \
      rB[s] = make_float4(0.f, 0.f, 0.f, 0.f);                                 \
    }                                                                          \
  }

  // prologue: rows h0-2 .. h0+2 into slots 6,7,0,1,2
  LOADR(6, h0 - 2)
  LOADR(7, h0 - 1)
  LOADR(0, h0)
  LOADR(1, h0 + 1)
  LOADR(2, h0 + 2)

#pragma unroll
  for (int hh = 0; hh < 16; ++hh) {
    if (hh < nrows) {
      const int h = h0 + hh;
      // prefetch row h+3 into slot (hh+3)&7 (row h-5 is dead)
      LOADR((hh + 3) & 7, h + 3)

      const int sm2 = (hh + 6) & 7, sm1 = (hh + 7) & 7;
      const int s00 = hh & 7, sp1 = (hh + 1) & 7;
      // vertical: v[w] = x[h-2] + 3x[h-1] + 3x[h] + x[h+1]
      float v0 = (rA[sm2].x + rA[sp1].x) + 3.f * (rA[sm1].x + rA[s00].x);
      float v1 = (rA[sm2].y + rA[sp1].y) + 3.f * (rA[sm1].y + rA[s00].y);
      float v2 = (rA[sm2].z + rA[sp1].z) + 3.f * (rA[sm1].z + rA[s00].z);
      float v3 = (rA[sm2].w + rA[sp1].w) + 3.f * (rA[sm1].w + rA[s00].w);
      float v4 = (rB[sm2].x + rB[sp1].x) + 3.f * (rB[sm1].x + rB[s00].x);
      float v5 = (rB[sm2].y + rB[sp1].y) + 3.f * (rB[sm1].y + rB[s00].y);
      float v6 = (rB[sm2].z + rB[sp1].z) + 3.f * (rB[sm1].z + rB[s00].z);
      float v7 = (rB[sm2].w + rB[sp1].w) + 3.f * (rB[sm1].w + rB[s00].w);

      // w-halo via shuffles (lane +-1 within the same c-group of 8)
      float vm1 = __shfl_up(v7, 1);
      float vm2 = __shfl_up(v6, 1);
      float vp  = __shfl_down(v0, 1);
      if (o == 0) { vm1 = 0.f; vm2 = 0.f; }
      if (o == 7) vp = 0.f;

      // horizontal + 1/64 scale
      const float S = 0.015625f;
      float g0 = ((vm2 + v1) + 3.f * (vm1 + v0)) * S;
      float g1 = ((vm1 + v2) + 3.f * (v0 + v1)) * S;
      float g2 = ((v0 + v3) + 3.f * (v1 + v2)) * S;
      float g3 = ((v1 + v4) + 3.f * (v2 + v3)) * S;
      float g4 = ((v2 + v5) + 3.f * (v3 + v4)) * S;
      float g5 = ((v3 + v6) + 3.f * (v4 + v5)) * S;
      float g6 = ((v4 + v7) + 3.f * (v5 + v6)) * S;
      float g7 = ((v5 + vp) + 3.f * (v6 + v7)) * S;

      unsigned d0, d1, d2, d3;
      CVTPK(d0, g0, g1);
      CVTPK(d1, g2, g3);
      CVTPK(d2, g4, g5);
      CVTPK(d3, g6, g7);
      *(uint4*)&stage[c * 80 + ((o ^ c) << 3)] = make_uint4(d0, d1, d2, d3);
      if (o == 7)                                  // out[w=64] = v[62] + 3 v[63]
        stage[c * 80 + 64] = f2bf((v6 + 3.f * v7) * S);
      __builtin_amdgcn_wave_barrier();

      // transpose read + NHWC store: lane w reads 8 channels
      u16x8 pk;
#pragma unroll
      for (int cc = 0; cc < 8; ++cc)
        pk[cc] = stage[cc * 80 + (((lane >> 3) ^ cc) << 3) + (lane & 7)];
      *(u16x8*)&xft[((size_t)(b * 4225 + h * 65 + lane) << 8) + cw] = pk;
      if (lane == 0) {
        u16x8 p2;
#pragma unroll
        for (int cc = 0; cc < 8; ++cc) p2[cc] = stage[cc * 80 + 64];
        *(u16x8*)&xft[((size_t)(b * 4225 + h * 65 + 64) << 8) + cw] = p2;
      }
      __builtin_amdgcn_wave_barrier();
    }
  }
}

// ---------------- Kernel 2: implicit-conv GEMM (proven), BK=128 -----------------
// C[oc=256][n=16384]; BM=128, BN=64, BK=128; 256 thr (4 waves 2m x 2n, 64x32 each)
__global__ __launch_bounds__(256) void k_gemm3(const ushort* __restrict__ Wb,
                                               const ushort* __restrict__ Xt,
                                               const float* __restrict__ bias,
                                               float* __restrict__ out) {
  __shared__ ushort lA[128 * 128];                 // 32 KB
  __shared__ ushort lB[64 * 128];                  // 16 KB
  const int bid = blockIdx.x;                      // 0..511
  const int work = (bid & 7) * 64 + (bid >> 3);    // XCD-chunked bijective
  const int ntile = work >> 1;
  const int mtile = work & 1;
  const int m0 = mtile * 128;
  const int n0 = ntile * 64;
  const int t = threadIdx.x;
  const int wid = t >> 6, lane = t & 63;
  const int wm = wid >> 1, wn = wid & 1;
  const int lrow = lane & 15, kgrp = lane >> 4;

  const ushort* aB[8];
#pragma unroll
  for (int i = 0; i < 8; ++i) {
    int idx = i * 256 + t;
    int row = idx >> 4, gL = idx & 15;
    aB[i] = Wb + (size_t)(m0 + row) * KD + SWZ(gL, row) * 8;
  }
  const ushort* bB[4];
#pragma unroll
  for (int i = 0; i < 4; ++i) {
    int idx = i * 256 + t;
    int row = idx >> 4, gL = idx & 15;
    int n = n0 + row;
    int b = n >> 10, oh = (n >> 5) & 31, ow = n & 31;
    bB[i] = Xt + ((size_t)((b * 65 + 2 * oh) * 65 + 2 * ow) << 8) +
            SWZ(gL, row) * 8;
  }

  f32x4 acc[4][2];
#pragma unroll
  for (int i = 0; i < 4; ++i)
#pragma unroll
    for (int j = 0; j < 2; ++j) acc[i][j] = (f32x4){0.f, 0.f, 0.f, 0.f};

  for (int kt = 0; kt < 18; ++kt) {
    const int j = kt >> 1;
    const int dh = j / 3, dw = j - 3 * dh;
    const int boff = (dh * 65 + dw) * 256 + ((kt & 1) << 7);
    const int k0 = kt << 7;
    __syncthreads();
#pragma unroll
    for (int i = 0; i < 8; ++i)
      GLDS16(aB[i] + k0, &lA[(i * 256 + t) * 8]);
#pragma unroll
    for (int i = 0; i < 4; ++i)
      GLDS16(bB[i] + boff, &lB[(i * 256 + t) * 8]);
    __syncthreads();

#pragma unroll
    for (int s = 0; s < 4; ++s) {
      bf16x8 Af[4], Bf[2];
#pragma unroll
      for (int f = 0; f < 4; ++f) {
        int row = wm * 64 + f * 16 + lrow;
        Af[f] = *(const bf16x8*)&lA[row * 128 + SWZ(s * 4 + kgrp, row) * 8];
      }
#pragma unroll
      for (int f = 0; f < 2; ++f) {
        int row = wn * 32 + f * 16 + lrow;
        Bf[f] = *(const bf16x8*)&lB[row * 128 + SWZ(s * 4 + kgrp, row) * 8];
      }
#pragma unroll
      for (int fm = 0; fm < 4; ++fm)
#pragma unroll
        for (int fn = 0; fn < 2; ++fn)
          acc[fm][fn] = __builtin_amdgcn_mfma_f32_16x16x32_bf16(
              Af[fm], Bf[fn], acc[fm][fn], 0, 0, 0);
    }
  }

  f32x4 bv[4];
#pragma unroll
  for (int fm = 0; fm < 4; ++fm)
    bv[fm] = *(const f32x4*)(bias + m0 + wm * 64 + fm * 16 + kgrp * 4);

#pragma unroll
  for (int fm = 0; fm < 4; ++fm) {
#pragma unroll
    for (int fn = 0; fn < 2; ++fn) {
      int nn = n0 + wn * 32 + fn * 16 + lrow;
      int oc = m0 + wm * 64 + fm * 16 + kgrp * 4;
      float* op = out + (size_t)(nn >> 10) * OUT_PER_B + (nn & 1023) +
                  (size_t)oc * 1024;
      op[0]    = acc[fm][fn][0] + bv[fm][0];
      op[1024] = acc[fm][fn][1] + bv[fm][1];
      op[2048] = acc[fm][fn][2] + bv[fm][2];
      op[3072] = acc[fm][fn][3] + bv[fm][3];
    }
  }
}

extern "C" void kernel_launch(void* const* d_in, const int* in_sizes, int n_in,
                              void* d_out, int out_size, void* d_ws, size_t ws_size,
                              hipStream_t stream) {
  const float* x    = (const float*)d_in[0];  // [16,256,64,64]
  const float* w    = (const float*)d_in[1];  // [256,256,3,3]
  const float* bias = (const float*)d_in[2];  // [256]
  float* out = (float*)d_out;                 // [16,256,32,32]

  char* ws = (char*)d_ws;
  ushort* xft = (ushort*)ws;                        // 16*4225*256*2 = 34,611,200 B
  ushort* wb  = (ushort*)(ws + 34611200);           // 1,179,648 B

  k_fir5<<<dim3(5, 8, 16), 256, 0, stream>>>(x, xft, w, wb);
  k_gemm3<<<512, 256, 0, stream>>>(wb, xft, bias, out);
}

// Round 16
// 60.100 us; speedup vs baseline: 1.5286x; 1.0230x over previous
//
#include <hip/hip_runtime.h>
#include <hip/hip_bf16.h>

typedef __attribute__((ext_vector_type(8))) short bf16x8;
typedef __attribute__((ext_vector_type(4))) float f32x4;
typedef __attribute__((ext_vector_type(8))) unsigned short u16x8;

#define KD 2304
#define OUT_PER_B (256 * 1024)
#define CGPL 67600                      // 16*4225: hw-elems per cg plane (x32 ch)

static __device__ __forceinline__ ushort f2bf(float f) {
  union { float f; unsigned int i; } v; v.f = f;
  unsigned int x = v.i;
  x += 0x7fffu + ((x >> 16) & 1u);   // round-to-nearest-even
  return (ushort)(x >> 16);
}

#define GLDS16(gp, lp)                                                         \
  __builtin_amdgcn_global_load_lds(                                            \
      (const __attribute__((address_space(1))) void*)(gp),                     \
      (__attribute__((address_space(3))) void*)(lp), 16, 0, 0)

// swizzle: 16-B chunk g (0..15) of row r -> XOR low 3 bits with r&7 (involution)
#define SWZ(g, r) (((g) & 8) | (((g) ^ (r)) & 7))

#define CVTPK(d, lo, hi) \
  asm("v_cvt_pk_bf16_f32 %0, %1, %2" : "=v"(d) : "v"(lo), "v"(hi))

// ---------------- Kernel 1: fused FIR(v->h) + transpose + weight cast -----------
// xft layout: [cg=8][b=16][hw=4225][32ch] bf16 -> wave stores 16 B at 64-B stride
// and the block's 4 waves (wid*8 ch) tile each 64-B line -> coalesced full lines.
__global__ __launch_bounds__(256) void k_fir5(const float* __restrict__ x,
                                              ushort* __restrict__ xft,
                                              const float* __restrict__ wsrc,
                                              ushort* __restrict__ wb) {
  __shared__ ushort stageAll[4][8 * 80];     // per-wave [c][80] ushorts
  const int band = blockIdx.x;               // 0..4; h0 = band*16
  const int cg = blockIdx.y;                 // 0..7
  const int b = blockIdx.z;                  // 0..15
  const int t = threadIdx.x;
  const int wid = t >> 6, lane = t & 63;
  const int c = lane >> 3, o = lane & 7;
  const int cw = cg * 32 + wid * 8;          // wave channel base (global)
  const int h0 = band * 16;
  const int nrows = (band == 4) ? 1 : 16;
  ushort* stage = stageAll[wid];
  // output plane base for this (cg, b): elem index *32 later
  const size_t obase = (size_t)(cg * 16 + b) * 4225;

  // fused weight cast, grid-stride (640 blocks x 256 thr)
  {
    int flat = band + 5 * (cg + 8 * b);
    for (int iw = flat * 256 + t; iw < 589824; iw += 163840) {
      float v = wsrc[iw];
      int j = iw % 9;
      int t2 = iw / 9;
      wb[(t2 >> 8) * KD + j * 256 + (t2 & 255)] = f2bf(v);
    }
  }

  const float* xrow = x + ((size_t)(b * 256 + cw + c) << 12) + o * 8;

  float4 rA[8], rB[8];
#define LOADR(s, r)                                                            \
  {                                                                            \
    if ((unsigned)(r) < 64u) {                                                 \
      rA[s] = *(const float4*)(xrow + (r) * 64);                               \
      rB[s] = *(const float4*)(xrow + (r) * 64 + 4);                           \
    } else {                                                                   \
      rA[s] = make_float4(0.f, 0.f, 0.f, 0.f);                                 \
      rB[s] = make_float4(0.f, 0.f, 0.f, 0.f);                                 \
    }                                                                          \
  }

  // prologue: rows h0-2 .. h0+2 into slots 6,7,0,1,2
  LOADR(6, h0 - 2)
  LOADR(7, h0 - 1)
  LOADR(0, h0)
  LOADR(1, h0 + 1)
  LOADR(2, h0 + 2)

#pragma unroll
  for (int hh = 0; hh < 16; ++hh) {
    if (hh < nrows) {
      const int h = h0 + hh;
      LOADR((hh + 3) & 7, h + 3)

      const int sm2 = (hh + 6) & 7, sm1 = (hh + 7) & 7;
      const int s00 = hh & 7, sp1 = (hh + 1) & 7;
      float v0 = (rA[sm2].x + rA[sp1].x) + 3.f * (rA[sm1].x + rA[s00].x);
      float v1 = (rA[sm2].y + rA[sp1].y) + 3.f * (rA[sm1].y + rA[s00].y);
      float v2 = (rA[sm2].z + rA[sp1].z) + 3.f * (rA[sm1].z + rA[s00].z);
      float v3 = (rA[sm2].w + rA[sp1].w) + 3.f * (rA[sm1].w + rA[s00].w);
      float v4 = (rB[sm2].x + rB[sp1].x) + 3.f * (rB[sm1].x + rB[s00].x);
      float v5 = (rB[sm2].y + rB[sp1].y) + 3.f * (rB[sm1].y + rB[s00].y);
      float v6 = (rB[sm2].z + rB[sp1].z) + 3.f * (rB[sm1].z + rB[s00].z);
      float v7 = (rB[sm2].w + rB[sp1].w) + 3.f * (rB[sm1].w + rB[s00].w);

      float vm1 = __shfl_up(v7, 1);
      float vm2 = __shfl_up(v6, 1);
      float vp  = __shfl_down(v0, 1);
      if (o == 0) { vm1 = 0.f; vm2 = 0.f; }
      if (o == 7) vp = 0.f;

      const float S = 0.015625f;
      float g0 = ((vm2 + v1) + 3.f * (vm1 + v0)) * S;
      float g1 = ((vm1 + v2) + 3.f * (v0 + v1)) * S;
      float g2 = ((v0 + v3) + 3.f * (v1 + v2)) * S;
      float g3 = ((v1 + v4) + 3.f * (v2 + v3)) * S;
      float g4 = ((v2 + v5) + 3.f * (v3 + v4)) * S;
      float g5 = ((v3 + v6) + 3.f * (v4 + v5)) * S;
      float g6 = ((v4 + v7) + 3.f * (v5 + v6)) * S;
      float g7 = ((v5 + vp) + 3.f * (v6 + v7)) * S;

      unsigned d0, d1, d2, d3;
      CVTPK(d0, g0, g1);
      CVTPK(d1, g2, g3);
      CVTPK(d2, g4, g5);
      CVTPK(d3, g6, g7);
      *(uint4*)&stage[c * 80 + ((o ^ c) << 3)] = make_uint4(d0, d1, d2, d3);
      if (o == 7)
        stage[c * 80 + 64] = f2bf((v6 + 3.f * v7) * S);
      __builtin_amdgcn_wave_barrier();

      // transpose read + store: lane w -> 16 B at 64-B stride (4 waves tile line)
      u16x8 pk;
#pragma unroll
      for (int cc = 0; cc < 8; ++cc)
        pk[cc] = stage[cc * 80 + (((lane >> 3) ^ cc) << 3) + (lane & 7)];
      *(u16x8*)&xft[((obase + h * 65 + lane) << 5) + wid * 8] = pk;
      if (lane == 0) {
        u16x8 p2;
#pragma unroll
        for (int cc = 0; cc < 8; ++cc) p2[cc] = stage[cc * 80 + 64];
        *(u16x8*)&xft[((obase + h * 65 + 64) << 5) + wid * 8] = p2;
      }
      __builtin_amdgcn_wave_barrier();
    }
  }
}

// ---------------- Kernel 2: implicit-conv GEMM, BK=128, new B layout ------------
// C[oc=256][n=16384]; BM=128, BN=64, BK=128; 256 thr (4 waves 2m x 2n, 64x32 each)
// B chunk g of slice kt lives in plane cg = (kt&1)*4 + (g>>2), sub (g&3)*8.
__global__ __launch_bounds__(256) void k_gemm3(const ushort* __restrict__ Wb,
                                               const ushort* __restrict__ Xt,
                                               const float* __restrict__ bias,
                                               float* __restrict__ out) {
  __shared__ ushort lA[128 * 128];                 // 32 KB
  __shared__ ushort lB[64 * 128];                  // 16 KB
  const int bid = blockIdx.x;                      // 0..511
  const int work = (bid & 7) * 64 + (bid >> 3);    // XCD-chunked bijective
  const int ntile = work >> 1;
  const int mtile = work & 1;
  const int m0 = mtile * 128;
  const int n0 = ntile * 64;
  const int t = threadIdx.x;
  const int wid = t >> 6, lane = t & 63;
  const int wm = wid >> 1, wn = wid & 1;
  const int lrow = lane & 15, kgrp = lane >> 4;

  const ushort* aB[8];
#pragma unroll
  for (int i = 0; i < 8; ++i) {
    int idx = i * 256 + t;
    int row = idx >> 4, gL = idx & 15;
    aB[i] = Wb + (size_t)(m0 + row) * KD + SWZ(gL, row) * 8;
  }
  const ushort* bB[4];
#pragma unroll
  for (int i = 0; i < 4; ++i) {
    int idx = i * 256 + t;
    int row = idx >> 4, gL = idx & 15;
    int sg = SWZ(gL, row);
    int n = n0 + row;
    int b = n >> 10, oh = (n >> 5) & 31, ow = n & 31;
    bB[i] = Xt +
            (((size_t)((sg >> 2) * 16 + b) * 4225 + (2 * oh) * 65 + 2 * ow) << 5) +
            (sg & 3) * 8;
  }

  f32x4 acc[4][2];
#pragma unroll
  for (int i = 0; i < 4; ++i)
#pragma unroll
    for (int j = 0; j < 2; ++j) acc[i][j] = (f32x4){0.f, 0.f, 0.f, 0.f};

  for (int kt = 0; kt < 18; ++kt) {
    const int j = kt >> 1;
    const int dh = j / 3, dw = j - 3 * dh;
    const int boff = (dh * 65 + dw) * 32 + (kt & 1) * (4 * CGPL * 32);
    const int k0 = kt << 7;
    __syncthreads();
#pragma unroll
    for (int i = 0; i < 8; ++i)
      GLDS16(aB[i] + k0, &lA[(i * 256 + t) * 8]);
#pragma unroll
    for (int i = 0; i < 4; ++i)
      GLDS16(bB[i] + boff, &lB[(i * 256 + t) * 8]);
    __syncthreads();

#pragma unroll
    for (int s = 0; s < 4; ++s) {
      bf16x8 Af[4], Bf[2];
#pragma unroll
      for (int f = 0; f < 4; ++f) {
        int row = wm * 64 + f * 16 + lrow;
        Af[f] = *(const bf16x8*)&lA[row * 128 + SWZ(s * 4 + kgrp, row) * 8];
      }
#pragma unroll
      for (int f = 0; f < 2; ++f) {
        int row = wn * 32 + f * 16 + lrow;
        Bf[f] = *(const bf16x8*)&lB[row * 128 + SWZ(s * 4 + kgrp, row) * 8];
      }
#pragma unroll
      for (int fm = 0; fm < 4; ++fm)
#pragma unroll
        for (int fn = 0; fn < 2; ++fn)
          acc[fm][fn] = __builtin_amdgcn_mfma_f32_16x16x32_bf16(
              Af[fm], Bf[fn], acc[fm][fn], 0, 0, 0);
    }
  }

  f32x4 bv[4];
#pragma unroll
  for (int fm = 0; fm < 4; ++fm)
    bv[fm] = *(const f32x4*)(bias + m0 + wm * 64 + fm * 16 + kgrp * 4);

#pragma unroll
  for (int fm = 0; fm < 4; ++fm) {
#pragma unroll
    for (int fn = 0; fn < 2; ++fn) {
      int nn = n0 + wn * 32 + fn * 16 + lrow;
      int oc = m0 + wm * 64 + fm * 16 + kgrp * 4;
      float* op = out + (size_t)(nn >> 10) * OUT_PER_B + (nn & 1023) +
                  (size_t)oc * 1024;
      op[0]    = acc[fm][fn][0] + bv[fm][0];
      op[1024] = acc[fm][fn][1] + bv[fm][1];
      op[2048] = acc[fm][fn][2] + bv[fm][2];
      op[3072] = acc[fm][fn][3] + bv[fm][3];
    }
  }
}

extern "C" void kernel_launch(void* const* d_in, const int* in_sizes, int n_in,
                              void* d_out, int out_size, void* d_ws, size_t ws_size,
                              hipStream_t stream) {
  const float* x    = (const float*)d_in[0];  // [16,256,64,64]
  const float* w    = (const float*)d_in[1];  // [256,256,3,3]
  const float* bias = (const float*)d_in[2];  // [256]
  float* out = (float*)d_out;                 // [16,256,32,32]

  char* ws = (char*)d_ws;
  ushort* xft = (ushort*)ws;                        // 8*16*4225*32*2 = 34,611,200 B
  ushort* wb  = (ushort*)(ws + 34611200);           // 1,179,648 B

  k_fir5<<<dim3(5, 8, 16), 256, 0, stream>>>(x, xft, w, wb);
  k_gemm3<<<512, 256, 0, stream>>>(wb, xft, bias, out);
}